// Round 1
// 69.972 us; speedup vs baseline: 1.0731x; 1.0731x over previous
//
#include <hip/hip_runtime.h>

// KAN 2x2 convolution, stride 1, summed over C=16 input channels.
// x: (8,16,128,128) fp32 -> out: (8,1,127,127) fp32
//
// Round-3 structure (from round-2's 75 us):
//  - channel reduction in REGISTERS: one block owns a 32x8 output tile for ALL
//    16 channels. Each thread owns one input position of the 33x9 tile and
//    accumulates spline sums (4 regs) + silu sum (1 reg) over the 16 channels,
//    writing the 4 per-position features to LDS exactly once. The window
//    gather then runs once per output (4 LDS reads, was 16), and outputs are
//    written with plain stores: NO atomicAdd, NO zero-memset dispatch,
//    2 barriers per block (was 8+).
//  - coef table padded to stride 5*float4: the old [11][4] layout put every
//    lane's float4 read into 2 bank groups (~6-way conflict on all 4 reads of
//    every eval); stride 5 spreads tc over 8 groups -> <=2-way (free).
//  - phase A balanced: 320 threads, exactly 1 value/thread (297 active),
//    16 independent global loads issued up-front per thread for ILP latency
//    hiding (grid = 512 blocks = 2 blocks/CU, 10 waves/CU).

#define IN_F 4
#define N_COEF 8
#define N_INT 11   // knot intervals
#define TW 32      // output tile width
#define TH 8       // output tile height
#define LW 33      // input tile width  (TW+1)
#define LH 9       // input tile height (TH+1)
#define NV (LW * LH)  // 297 input positions per tile
#define NC 16      // channels, all handled by one block
#define NT 320     // 5 waves: 297 phase-A lanes, 256 gather lanes

__device__ __forceinline__ float silu_f(float x) {
    return x * __builtin_amdgcn_rcpf(1.0f + __expf(-x));
}

__global__ __launch_bounds__(NT) void kan_conv_kernel(
    const float* __restrict__ x,
    const float* __restrict__ base_w,    // (1,4)
    const float* __restrict__ spline_w,  // (1,4,8)
    const float* __restrict__ spline_s,  // (1,4)
    const float* __restrict__ grid,      // (4,12) identical uniform rows
    float* __restrict__ out,
    int B, int C, int H, int W)
{
    const int Ho = H - 1, Wo = W - 1;

    __shared__ float4 coef[N_INT][IN_F + 1];  // stride-5 float4: <=2-way banks
    __shared__ float  sfeat[IN_F][NV + 7];    // plane stride 304: conflict-free
    __shared__ float  s_misc[6];              // bw0..3, g0, invh

    const int tid = threadIdx.x;

    // ---- one-time table build (tid 0..43): fold spline weights into
    //      per-(interval, position) power-basis cubics ----
    if (tid < N_INT * IN_F) {
        const int t = tid >> 2;
        const int p = tid & 3;
        // uniform cubic B-spline blending matrix (power basis in u)
        const float M[4][4] = {
            {1.f/6.f, -3.f/6.f,  3.f/6.f, -1.f/6.f},
            {4.f/6.f,  0.f,     -6.f/6.f,  3.f/6.f},
            {1.f/6.f,  3.f/6.f,  3.f/6.f, -3.f/6.f},
            {0.f,      0.f,      0.f,      1.f/6.f}};
        const float scal = spline_s[p];
        float c0 = 0.f, c1 = 0.f, c2 = 0.f, c3 = 0.f;
        #pragma unroll
        for (int m = 0; m < 4; ++m) {
            const int j = t - 3 + m;
            const float w = (j >= 0 && j < N_COEF)
                              ? spline_w[p * N_COEF + j] * scal : 0.f;
            c0 += M[m][0] * w; c1 += M[m][1] * w;
            c2 += M[m][2] * w; c3 += M[m][3] * w;
        }
        coef[t][p] = make_float4(c0, c1, c2, c3);
    }
    if (tid < IN_F) s_misc[tid] = base_w[tid];
    if (tid == 4)   s_misc[4] = grid[0];
    if (tid == 5)   s_misc[5] = 1.0f / (grid[1] - grid[0]);

    // ---- block decomposition: 4 xtiles x 16 ytiles x 8 batches = 512 ----
    int bid = blockIdx.x;
    const int txi = bid & 3;  bid >>= 2;
    const int tyi = bid & 15; bid >>= 4;
    const int b   = bid;
    const int tx0 = txi * TW, ty0 = tyi * TH;

    __syncthreads();

    const float g0 = s_misc[4], invh = s_misc[5];

    // ---- phase A: one input position per thread, all 16 channels,
    //      accumulate in registers, write LDS once ----
    if (tid < NV) {
        const int r  = tid / LW;
        const int cc = tid - r * LW;
        const int iy = ty0 + r, ix = tx0 + cc;
        const bool inb = (iy < H) & (ix < W);
        const size_t cs = (size_t)H * W;
        const float* __restrict__ px =
            x + (size_t)b * C * cs + (inb ? (iy * W + ix) : 0);

        float vals[NC];
        #pragma unroll
        for (int c = 0; c < NC; ++c) vals[c] = px[c * cs];

        float a0 = 0.f, a1 = 0.f, a2 = 0.f, a3 = 0.f, ssum = 0.f;
        #pragma unroll
        for (int c = 0; c < NC; ++c) {
            const float val = inb ? vals[c] : 0.f;
            ssum += silu_f(val);
            const float tf  = (val - g0) * invh;
            const float tfl = floorf(tf);
            const int   ti  = (int)tfl;
            const float u   = tf - tfl;
            const bool  valid = ((unsigned)ti < (unsigned)N_INT);
            const int   tc  = valid ? ti : 0;
            const float4 f0 = coef[tc][0];
            const float4 f1 = coef[tc][1];
            const float4 f2 = coef[tc][2];
            const float4 f3 = coef[tc][3];
            float s0 = fmaf(u, f0.w, f0.z); s0 = fmaf(u, s0, f0.y); s0 = fmaf(u, s0, f0.x);
            float s1 = fmaf(u, f1.w, f1.z); s1 = fmaf(u, s1, f1.y); s1 = fmaf(u, s1, f1.x);
            float s2 = fmaf(u, f2.w, f2.z); s2 = fmaf(u, s2, f2.y); s2 = fmaf(u, s2, f2.x);
            float s3 = fmaf(u, f3.w, f3.z); s3 = fmaf(u, s3, f3.y); s3 = fmaf(u, s3, f3.x);
            a0 += valid ? s0 : 0.f;
            a1 += valid ? s1 : 0.f;
            a2 += valid ? s2 : 0.f;
            a3 += valid ? s3 : 0.f;
        }
        const float bw0 = s_misc[0], bw1 = s_misc[1];
        const float bw2 = s_misc[2], bw3 = s_misc[3];
        sfeat[0][tid] = fmaf(ssum, bw0, a0);
        sfeat[1][tid] = fmaf(ssum, bw1, a1);
        sfeat[2][tid] = fmaf(ssum, bw2, a2);
        sfeat[3][tid] = fmaf(ssum, bw3, a3);
    }

    __syncthreads();

    // ---- phase B: gather 4 window neighbors, direct store ----
    if (tid < TW * TH) {
        const int lx = tid & (TW - 1);
        const int ly = tid >> 5;
        const int oy = ty0 + ly, ox = tx0 + lx;
        const int i00 = ly * LW + lx;
        const float acc = sfeat[0][i00] + sfeat[1][i00 + 1]
                        + sfeat[2][i00 + LW] + sfeat[3][i00 + LW + 1];
        if (oy < Ho && ox < Wo)
            out[((size_t)b * Ho + oy) * Wo + ox] = acc;
    }
}

extern "C" void kernel_launch(void* const* d_in, const int* in_sizes, int n_in,
                              void* d_out, int out_size, void* d_ws, size_t ws_size,
                              hipStream_t stream) {
    const float* x        = (const float*)d_in[0];
    const float* base_w   = (const float*)d_in[1];
    const float* spline_w = (const float*)d_in[2];
    const float* spline_s = (const float*)d_in[3];
    const float* grid     = (const float*)d_in[4];
    float* out = (float*)d_out;

    const int B = 8, C = 16, H = 128, W = 128;

    // 4 xtiles x 16 ytiles x 8 batches = 512 blocks; every output written
    // exactly once -> no memset, no atomics, single dispatch.
    kan_conv_kernel<<<512, NT, 0, stream>>>(
        x, base_w, spline_w, spline_s, grid, out, B, C, H, W);
}

// Round 2
// 68.455 us; speedup vs baseline: 1.0968x; 1.0222x over previous
//
#include <hip/hip_runtime.h>

// KAN 2x2 convolution, stride 1, summed over C=16 input channels.
// x: (8,16,128,128) fp32 -> out: (8,1,127,127) fp32
//
// Round-4 structure (from round-3's 70.0 us):
//  - CHANNEL-SPLIT ACROSS WAVE GROUPS: block = 640 threads (10 waves).
//    Group 0 (tid 0..319) accumulates channels 0..7, group 1 (tid 320..639)
//    channels 8..15, each into its own sfeat partial; the gather sums both.
//    Same total lane-work as round 3, but waves/SIMD 2.5 -> 5 and the
//    per-thread serial channel chain halves (16 -> 8). The harness's 268 MB
//    poison-fill evicts L3 every replay, so first-use loads are cold HBM
//    (~900 cyc); this is a latency fix, not a throughput fix.
//  - ZERO COEF ROW: coef row 11 is all-zeros; out-of-grid values index it
//    (tc = valid ? ti : 11), removing 4 result cndmasks per eval.
//  - OOB values are DON'T-CARE: out-of-tile positions only feed outputs
//    masked at the store, so only the load ADDRESS is clamped; the
//    per-channel `inb ? val : 0` select is gone.
//  - single dispatch, no atomics, no memset, 2 barriers per block.

#define IN_F 4
#define N_COEF 8
#define N_INT 11      // valid knot intervals; row 11 of coef is zeros
#define TW 32         // output tile width
#define TH 8          // output tile height
#define LW 33         // input tile width  (TW+1)
#define LH 9          // input tile height (TH+1)
#define NV (LW * LH)  // 297 input positions per tile
#define CPG 8         // channels per group
#define GT 320        // threads per group (5 waves; 297 active)
#define NT (2 * GT)   // 640 threads, 10 waves

__device__ __forceinline__ float silu_f(float x) {
    return x * __builtin_amdgcn_rcpf(1.0f + __expf(-x));
}

__global__ __launch_bounds__(NT) void kan_conv_kernel(
    const float* __restrict__ x,
    const float* __restrict__ base_w,    // (1,4)
    const float* __restrict__ spline_w,  // (1,4,8)
    const float* __restrict__ spline_s,  // (1,4)
    const float* __restrict__ grid,      // (4,12) identical uniform rows
    float* __restrict__ out,
    int B, int C, int H, int W)
{
    const int Ho = H - 1, Wo = W - 1;

    __shared__ float4 coef[N_INT + 1][IN_F + 1];  // 12 x 5 float4, stride-5
    __shared__ float  sfeat[2][IN_F][NV + 7];     // per-group partials
    __shared__ float  s_misc[6];                  // bw0..3, g0, invh

    const int tid = threadIdx.x;

    // ---- one-time table build (tid 0..47): fold spline weights into
    //      per-(interval, position) power-basis cubics; t==11 -> all-zero row
    if (tid < (N_INT + 1) * IN_F) {
        const int t = tid >> 2;
        const int p = tid & 3;
        // uniform cubic B-spline blending matrix (power basis in u)
        const float M[4][4] = {
            {1.f/6.f, -3.f/6.f,  3.f/6.f, -1.f/6.f},
            {4.f/6.f,  0.f,     -6.f/6.f,  3.f/6.f},
            {1.f/6.f,  3.f/6.f,  3.f/6.f, -3.f/6.f},
            {0.f,      0.f,      0.f,      1.f/6.f}};
        const float scal = spline_s[p];
        float c0 = 0.f, c1 = 0.f, c2 = 0.f, c3 = 0.f;
        #pragma unroll
        for (int m = 0; m < 4; ++m) {
            const int j = t - 3 + m;
            const float w = (j >= 0 && j < N_COEF)
                              ? spline_w[p * N_COEF + j] * scal : 0.f;
            c0 += M[m][0] * w; c1 += M[m][1] * w;
            c2 += M[m][2] * w; c3 += M[m][3] * w;
        }
        coef[t][p] = make_float4(c0, c1, c2, c3);
    }
    if (tid < IN_F) s_misc[tid] = base_w[tid];
    if (tid == 4)   s_misc[4] = grid[0];
    if (tid == 5)   s_misc[5] = 1.0f / (grid[1] - grid[0]);

    // ---- block decomposition: 4 xtiles x 16 ytiles x 8 batches = 512 ----
    int bid = blockIdx.x;
    const int txi = bid & 3;  bid >>= 2;
    const int tyi = bid & 15; bid >>= 4;
    const int b   = bid;
    const int tx0 = txi * TW, ty0 = tyi * TH;

    const int grp = (tid >= GT) ? 1 : 0;
    const int lt  = tid - grp * GT;      // 0..319 within group

    __syncthreads();

    const float g0 = s_misc[4], invh = s_misc[5];

    // ---- phase A: one input position per thread, 8 channels per group,
    //      accumulate in registers, write LDS once ----
    if (lt < NV) {
        const int r  = lt / LW;
        const int cc = lt - r * LW;
        const int iy = ty0 + r, ix = tx0 + cc;
        // OOB positions feed only masked-out outputs: clamp ADDRESS only.
        const bool inb = (iy < H) & (ix < W);
        const size_t cs = (size_t)H * W;
        const float* __restrict__ px =
            x + ((size_t)b * C + grp * CPG) * cs + (inb ? (iy * W + ix) : 0);

        float vals[CPG];
        #pragma unroll
        for (int c = 0; c < CPG; ++c) vals[c] = px[c * cs];

        float a0 = 0.f, a1 = 0.f, a2 = 0.f, a3 = 0.f, ssum = 0.f;
        #pragma unroll
        for (int c = 0; c < CPG; ++c) {
            const float val = vals[c];
            ssum += silu_f(val);
            const float tf  = (val - g0) * invh;
            const float tfl = floorf(tf);
            const int   ti  = (int)tfl;
            const float u   = tf - tfl;
            // out-of-grid -> zero row 11 (spline contribution exactly 0)
            const int   tc  = ((unsigned)ti < (unsigned)N_INT) ? ti : N_INT;
            const float4 f0 = coef[tc][0];
            const float4 f1 = coef[tc][1];
            const float4 f2 = coef[tc][2];
            const float4 f3 = coef[tc][3];
            float s0 = fmaf(u, f0.w, f0.z); s0 = fmaf(u, s0, f0.y); s0 = fmaf(u, s0, f0.x);
            float s1 = fmaf(u, f1.w, f1.z); s1 = fmaf(u, s1, f1.y); s1 = fmaf(u, s1, f1.x);
            float s2 = fmaf(u, f2.w, f2.z); s2 = fmaf(u, s2, f2.y); s2 = fmaf(u, s2, f2.x);
            float s3 = fmaf(u, f3.w, f3.z); s3 = fmaf(u, s3, f3.y); s3 = fmaf(u, s3, f3.x);
            a0 += s0; a1 += s1; a2 += s2; a3 += s3;
        }
        const float bw0 = s_misc[0], bw1 = s_misc[1];
        const float bw2 = s_misc[2], bw3 = s_misc[3];
        sfeat[grp][0][lt] = fmaf(ssum, bw0, a0);
        sfeat[grp][1][lt] = fmaf(ssum, bw1, a1);
        sfeat[grp][2][lt] = fmaf(ssum, bw2, a2);
        sfeat[grp][3][lt] = fmaf(ssum, bw3, a3);
    }

    __syncthreads();

    // ---- phase B: gather 4 window neighbors from both group partials ----
    if (tid < TW * TH) {
        const int lx = tid & (TW - 1);
        const int ly = tid >> 5;
        const int oy = ty0 + ly, ox = tx0 + lx;
        const int i00 = ly * LW + lx;
        const float acc =
              sfeat[0][0][i00]          + sfeat[1][0][i00]
            + sfeat[0][1][i00 + 1]      + sfeat[1][1][i00 + 1]
            + sfeat[0][2][i00 + LW]     + sfeat[1][2][i00 + LW]
            + sfeat[0][3][i00 + LW + 1] + sfeat[1][3][i00 + LW + 1];
        if (oy < Ho && ox < Wo)
            out[((size_t)b * Ho + oy) * Wo + ox] = acc;
    }
}

extern "C" void kernel_launch(void* const* d_in, const int* in_sizes, int n_in,
                              void* d_out, int out_size, void* d_ws, size_t ws_size,
                              hipStream_t stream) {
    const float* x        = (const float*)d_in[0];
    const float* base_w   = (const float*)d_in[1];
    const float* spline_w = (const float*)d_in[2];
    const float* spline_s = (const float*)d_in[3];
    const float* grid     = (const float*)d_in[4];
    float* out = (float*)d_out;

    const int B = 8, C = 16, H = 128, W = 128;

    // 4 xtiles x 16 ytiles x 8 batches = 512 blocks x 640 threads;
    // every output written exactly once -> no memset, no atomics.
    kan_conv_kernel<<<512, NT, 0, stream>>>(
        x, base_w, spline_w, spline_s, grid, out, B, C, H, W);
}